// Round 1
// baseline (749.833 us; speedup 1.0000x reference)
//
#include <hip/hip_runtime.h>
#include <math.h>
#include <stdint.h>

// ---------------- dims ----------------
#define BETA 0.9f
#define THR 1.0f
#define T_STEPS 50
#define BN_EPS 1e-5f

#define NITEM 64          // 2 inputs x 32 batch
#define C1 16
#define L1 1981           // conv1 out length
#define L1P 1984          // padded
#define P4 495            // pooled length
#define PPAD 512          // pooled padded row bytes
#define C2 32
#define L2 493            // conv2 out length
#define L2PAD 496
#define KTOT 15872        // C2*L2PAD (padded flat dim)
#define KREAL 15776       // C2*L2
#define NFC 250
#define NPAD 256
#define KSPLIT 8
#define KRANGE 1984       // KTOT/KSPLIT
#define MROWS 3200        // T_STEPS*NITEM

// ---------------- workspace layout (bytes) ----------------
#define OFF_CUR1 0UL
#define OFF_POOL 8126464UL            // 64*16*1984*4
#define OFF_SPK2 34340864UL           // + 50*64*16*512
#define OFF_WT   85131264UL           // + 3200*15872
#define OFF_PART 101384192UL          // + 15872*256*4
#define OFF_COMB 127598592UL          // + 8*3200*256*4

// ---------------- K1: transpose fc1w [250,15776] -> wT [15872,256] (zero-padded) ----------------
__global__ __launch_bounds__(256) void k_wt(const float* __restrict__ fc1w,
                                            float* __restrict__ wT) {
  __shared__ float tile[64][65];
  int j0 = blockIdx.x * 64;
  int n0 = blockIdx.y * 64;
  int lane = threadIdx.x & 63;
  int quad = threadIdx.x >> 6;
  int jp = j0 + lane;
  int oc = jp / L2PAD;
  int pos = jp - oc * L2PAD;
  bool jvalid = (pos < L2);
  int jsrc = oc * L2 + pos;
#pragma unroll
  for (int i = 0; i < 16; ++i) {
    int n = n0 + quad * 16 + i;
    float vv = 0.f;
    if (jvalid && n < NFC) vv = fc1w[n * KREAL + jsrc];
    tile[lane][quad * 16 + i] = vv;
  }
  __syncthreads();
#pragma unroll
  for (int i = 0; i < 16; ++i) {
    int row = quad * 16 + i;
    wT[(j0 + row) * NPAD + n0 + lane] = tile[row][lane];
  }
}

// ---------------- K2: conv1 (K=80, stride4) + BN1 fold -> cur1 [64][16][1984] ----------------
__global__ __launch_bounds__(256) void k_conv1(const float* __restrict__ x1, const float* __restrict__ x2,
                                               const float* __restrict__ c1w, const float* __restrict__ c1b,
                                               const float* __restrict__ g, const float* __restrict__ bb,
                                               const float* __restrict__ mn, const float* __restrict__ vr,
                                               float* __restrict__ cur1) {
  __shared__ float xs[1104];
  int item = blockIdx.y;
  int pc = blockIdx.x;                 // 0..7
  int tid = threadIdx.x;
  const float* x = (item < 32 ? x1 : x2) + (item & 31) * 8000;
  int xoff = pc * 1024;
  for (int i = tid; i < 1100; i += 256) {
    int gi = xoff + i;
    xs[i] = (gi < 8000) ? x[gi] : 0.f;
  }
  __syncthreads();
  int p = pc * 256 + tid;
  bool pv = (p < L1);
  for (int c = 0; c < C1; ++c) {
    float s = g[c] / sqrtf(vr[c] + BN_EPS);
    float sh = (c1b[c] - mn[c]) * s + bb[c];
    const float* wr = c1w + c * 80;
    float acc = 0.f;
#pragma unroll 10
    for (int k = 0; k < 80; ++k) acc += wr[k] * xs[4 * tid + k];
    if (pv) cur1[(item * C1 + c) * L1P + p] = acc * s + sh;
  }
}

// ---------------- K3: LIF1 (all 50 steps) + maxpool4 -> pooled bytes [50][64][16][512] ----------------
__global__ __launch_bounds__(256) void k_lif1(const float* __restrict__ cur1,
                                              uint8_t* __restrict__ pooled) {
  int idx = blockIdx.x * 256 + threadIdx.x;
  if (idx >= NITEM * C1 * P4) return;
  int item = idx / (C1 * P4);
  int rem = idx - item * (C1 * P4);
  int c = rem / P4;
  int p4 = rem - c * P4;
  const float4 cv = *reinterpret_cast<const float4*>(cur1 + (item * C1 + c) * L1P + 4 * p4);
  float m0 = 0.f, m1 = 0.f, m2 = 0.f, m3 = 0.f;
  uint8_t* out = pooled + (item * C1 + c) * PPAD + p4;
  const int tstride = NITEM * C1 * PPAD;
  for (int t = 0; t < T_STEPS; ++t) {
    float r0 = (m0 > THR) ? 1.f : 0.f;
    float r1 = (m1 > THR) ? 1.f : 0.f;
    float r2 = (m2 > THR) ? 1.f : 0.f;
    float r3 = (m3 > THR) ? 1.f : 0.f;
    m0 = BETA * m0 + cv.x - r0;
    m1 = BETA * m1 + cv.y - r1;
    m2 = BETA * m2 + cv.z - r2;
    m3 = BETA * m3 + cv.w - r3;
    int spk = (m0 > THR) | (m1 > THR) | (m2 > THR) | (m3 > THR);
    out[t * tstride] = (uint8_t)spk;
  }
}

// ---------------- K4: conv2 + BN2 + LIF2 -> spk2 bytes [50*64][32][496] (u32 stores) ----------------
__global__ __launch_bounds__(512) void k_conv2(const uint8_t* __restrict__ pooled,
                                               const float* __restrict__ c2w, const float* __restrict__ c2b,
                                               const float* __restrict__ g, const float* __restrict__ bb,
                                               const float* __restrict__ mn, const float* __restrict__ vr,
                                               uint32_t* __restrict__ spk2) {
  __shared__ uint32_t pl[C1][132];
  int item = blockIdx.y;
  int pos0 = blockIdx.x * 64;
  int tid = threadIdx.x;
  int oc = tid >> 4;
  int pg = tid & 15;
  float s2 = g[oc] / sqrtf(vr[oc] + BN_EPS);
  float sh2 = (c2b[oc] - mn[oc]) * s2 + bb[oc];
  float w[48];
#pragma unroll
  for (int i = 0; i < 48; ++i) w[i] = c2w[oc * 48 + i] * s2;
  float mem0 = 0.f, mem1 = 0.f, mem2 = 0.f, mem3 = 0.f;
  int w0 = (pos0 >> 2) + pg;
  bool dostore = (pos0 + 4 * pg) < L2PAD;
  const uint32_t* gp = reinterpret_cast<const uint32_t*>(pooled) + item * (C1 * PPAD / 4);
  const int tstr = NITEM * C1 * PPAD / 4;
  int outbase = (item * KTOT + oc * L2PAD + pos0 + 4 * pg) >> 2;
  for (int t = 0; t < T_STEPS; ++t) {
    const uint32_t* gpt = gp + t * tstr;
    for (int i = tid; i < C1 * 128; i += 512) pl[i >> 7][i & 127] = gpt[i];
    __syncthreads();
    float c0 = sh2, c1v = sh2, c2v = sh2, c3v = sh2;
#pragma unroll
    for (int ic = 0; ic < C1; ++ic) {
      uint32_t wa = pl[ic][w0];
      uint32_t wb = pl[ic][w0 + 1];
      float f0 = (float)(wa & 0xffu);
      float f1 = (float)((wa >> 8) & 0xffu);
      float f2 = (float)((wa >> 16) & 0xffu);
      float f3 = (float)(wa >> 24);
      float f4 = (float)(wb & 0xffu);
      float f5 = (float)((wb >> 8) & 0xffu);
      float f6 = (float)((wb >> 16) & 0xffu);
      float wk0 = w[ic * 3 + 0], wk1 = w[ic * 3 + 1], wk2 = w[ic * 3 + 2];
      c0 += wk0 * f0; c0 += wk1 * f1; c0 += wk2 * f2;
      c1v += wk0 * f1; c1v += wk1 * f2; c1v += wk2 * f3;
      c2v += wk0 * f2; c2v += wk1 * f3; c2v += wk2 * f4;
      c3v += wk0 * f3; c3v += wk1 * f4; c3v += wk2 * f5;
      (void)f6;
    }
    uint32_t packed = 0;
    {
      float r = (mem0 > THR) ? 1.f : 0.f; mem0 = BETA * mem0 + c0 - r;  if (mem0 > THR) packed |= 1u;
    }
    {
      float r = (mem1 > THR) ? 1.f : 0.f; mem1 = BETA * mem1 + c1v - r; if (mem1 > THR) packed |= (1u << 8);
    }
    {
      float r = (mem2 > THR) ? 1.f : 0.f; mem2 = BETA * mem2 + c2v - r; if (mem2 > THR) packed |= (1u << 16);
    }
    {
      float r = (mem3 > THR) ? 1.f : 0.f; mem3 = BETA * mem3 + c3v - r; if (mem3 > THR) packed |= (1u << 24);
    }
    if (dostore) spk2[t * (NITEM * KTOT / 4) + outbase] = packed;
    __syncthreads();
  }
}

// ---------------- K5: fc1 GEMM  part[ks][3200][256] = A_bits[3200][KTOT] * wT[KTOT][256] ----------------
__global__ __launch_bounds__(512) void k_fc1(const uint8_t* __restrict__ spk2,
                                             const float* __restrict__ wT,
                                             float* __restrict__ part) {
  __shared__ __align__(16) float Al[32][64];
  __shared__ __align__(16) float Wl[32][256];
  int ks = blockIdx.x;                 // 0..7
  int m0 = blockIdx.y * 64;            // 0..3136
  int tid = threadIdx.x;
  int tm = tid >> 5;                   // 0..15
  int tn = tid & 31;                   // 0..31
  float acc[4][8];
#pragma unroll
  for (int r = 0; r < 4; ++r)
#pragma unroll
    for (int j = 0; j < 8; ++j) acc[r][j] = 0.f;
  const uint32_t* A32 = reinterpret_cast<const uint32_t*>(spk2);
  int sm = tid >> 3;                   // 0..63 (A staging row)
  int sq = tid & 7;                    // word within 32B
  int wr = tid >> 6;                   // 0..7 (W staging row base)
  int wc = tid & 63;                   // col quad
  for (int ch = 0; ch < 62; ++ch) {
    int k0 = ks * KRANGE + ch * 32;
    uint32_t a4 = A32[(((m0 + sm) * KTOT + k0) >> 2) + sq];
    Al[4 * sq + 0][sm] = (float)(a4 & 0xffu);
    Al[4 * sq + 1][sm] = (float)((a4 >> 8) & 0xffu);
    Al[4 * sq + 2][sm] = (float)((a4 >> 16) & 0xffu);
    Al[4 * sq + 3][sm] = (float)(a4 >> 24);
#pragma unroll
    for (int i = 0; i < 4; ++i) {
      int row = wr + 8 * i;
      float4 wv = *reinterpret_cast<const float4*>(wT + (k0 + row) * NPAD + 4 * wc);
      *reinterpret_cast<float4*>(&Wl[row][4 * wc]) = wv;
    }
    __syncthreads();
#pragma unroll
    for (int k = 0; k < 32; ++k) {
      float4 av = *reinterpret_cast<const float4*>(&Al[k][tm * 4]);
#pragma unroll
      for (int j = 0; j < 8; ++j) {
        float wv = Wl[k][tn + 32 * j];
        acc[0][j] += av.x * wv;
        acc[1][j] += av.y * wv;
        acc[2][j] += av.z * wv;
        acc[3][j] += av.w * wv;
      }
    }
    __syncthreads();
  }
#pragma unroll
  for (int r = 0; r < 4; ++r)
#pragma unroll
    for (int j = 0; j < 8; ++j)
      part[(ks * MROWS + m0 + tm * 4 + r) * NPAD + tn + 32 * j] = acc[r][j];
}

// ---------------- K6: reduce K-splits + fc1 bias + LIF3 + rate/latency -> comb [64][500] ----------------
__global__ __launch_bounds__(256) void k_lif3(const float* __restrict__ part,
                                              const float* __restrict__ fc1b,
                                              float* __restrict__ comb) {
  int item = blockIdx.x;
  int n = threadIdx.x;
  if (n >= NFC) return;
  float mem = 0.f, cnt = 0.f;
  int first = -1;
  float bias = fc1b[n];
  for (int t = 0; t < T_STEPS; ++t) {
    int row = t * NITEM + item;
    float s = bias;
#pragma unroll
    for (int ks = 0; ks < KSPLIT; ++ks) s += part[(ks * MROWS + row) * NPAD + n];
    float r = (mem > THR) ? 1.f : 0.f;
    mem = BETA * mem + s - r;
    if (mem > THR) { cnt += 1.f; if (first < 0) first = t; }
  }
  comb[item * 500 + n] = cnt;
  comb[item * 500 + NFC + n] = (first < 0) ? 0.f : ((float)first / (float)T_STEPS);
}

// ---------------- K7: head GEMM [64]x[500]->[128] + L2 normalize -> d_out ----------------
__global__ __launch_bounds__(128) void k_head(const float* __restrict__ comb,
                                              const float* __restrict__ fcsw,
                                              const float* __restrict__ fcsb,
                                              float* __restrict__ dout) {
  __shared__ float cr[500];
  __shared__ float red[2];
  int item = blockIdx.x;
  int o = threadIdx.x;
  for (int i = o; i < 500; i += 128) cr[i] = comb[item * 500 + i];
  __syncthreads();
  float acc = fcsb[o];
  for (int j = 0; j < 500; ++j) acc += cr[j] * fcsw[o * 500 + j];
  float sq = acc * acc;
  for (int off = 32; off > 0; off >>= 1) sq += __shfl_down(sq, off, 64);
  if ((o & 63) == 0) red[o >> 6] = sq;
  __syncthreads();
  float norm = sqrtf(red[0] + red[1]);
  norm = fmaxf(norm, 1e-12f);
  dout[item * 128 + o] = acc / norm;
}

// ---------------- launch ----------------
extern "C" void kernel_launch(void* const* d_in, const int* in_sizes, int n_in,
                              void* d_out, int out_size, void* d_ws, size_t ws_size,
                              hipStream_t stream) {
  const float* x1   = (const float*)d_in[0];
  const float* x2   = (const float*)d_in[1];
  const float* c1w  = (const float*)d_in[2];
  const float* c1b  = (const float*)d_in[3];
  const float* bn1g = (const float*)d_in[4];
  const float* bn1b = (const float*)d_in[5];
  const float* bn1m = (const float*)d_in[6];
  const float* bn1v = (const float*)d_in[7];
  const float* c2w  = (const float*)d_in[8];
  const float* c2b  = (const float*)d_in[9];
  const float* bn2g = (const float*)d_in[10];
  const float* bn2b = (const float*)d_in[11];
  const float* bn2m = (const float*)d_in[12];
  const float* bn2v = (const float*)d_in[13];
  const float* fc1w = (const float*)d_in[14];
  const float* fc1b = (const float*)d_in[15];
  const float* fcsw = (const float*)d_in[16];
  const float* fcsb = (const float*)d_in[17];

  char* ws = (char*)d_ws;
  float*    cur1   = (float*)(ws + OFF_CUR1);
  uint8_t*  pooled = (uint8_t*)(ws + OFF_POOL);
  uint8_t*  spk2   = (uint8_t*)(ws + OFF_SPK2);
  float*    wT     = (float*)(ws + OFF_WT);
  float*    part   = (float*)(ws + OFF_PART);
  float*    comb   = (float*)(ws + OFF_COMB);

  k_wt<<<dim3(KTOT / 64, NPAD / 64), dim3(256), 0, stream>>>(fc1w, wT);
  k_conv1<<<dim3(8, NITEM), dim3(256), 0, stream>>>(x1, x2, c1w, c1b, bn1g, bn1b, bn1m, bn1v, cur1);
  k_lif1<<<dim3((NITEM * C1 * P4) / 256), dim3(256), 0, stream>>>(cur1, pooled);
  k_conv2<<<dim3(8, NITEM), dim3(512), 0, stream>>>(pooled, c2w, c2b, bn2g, bn2b, bn2m, bn2v,
                                                    (uint32_t*)spk2);
  k_fc1<<<dim3(KSPLIT, MROWS / 64), dim3(512), 0, stream>>>(spk2, wT, part);
  k_lif3<<<dim3(NITEM), dim3(256), 0, stream>>>(part, fc1b, comb);
  k_head<<<dim3(NITEM), dim3(128), 0, stream>>>(comb, fcsw, fcsb, (float*)d_out);
}

// Round 2
// 406.750 us; speedup vs baseline: 1.8435x; 1.8435x over previous
//
#include <hip/hip_runtime.h>
#include <math.h>
#include <stdint.h>

// ---------------- dims ----------------
#define BETA 0.9f
#define THR 1.0f
#define T_STEPS 50
#define BN_EPS 1e-5f

#define NITEM 64          // 2 inputs x 32 batch
#define C1 16
#define L1 1981           // conv1 out length
#define L1P 1984          // padded
#define P4 495            // pooled length
#define PPAD 512          // pooled padded row bytes
#define C2 32
#define L2 493            // conv2 out length
#define L2PAD 496
#define KTOT 15872        // C2*L2PAD (padded flat dim)
#define KREAL 15776       // C2*L2
#define NFC 250
#define NPAD 256
#define KSPLIT 8
#define KRANGE 1984       // KTOT/KSPLIT
#define KSTEPS 62         // KRANGE/32
#define NKTILE 496        // KTOT/32
#define MROWS 3200        // T_STEPS*NITEM

// ---------------- workspace layout (bytes) — unchanged from passing round ----------------
#define OFF_CUR1 0UL
#define OFF_POOL 8126464UL            // 64*16*1984*4
#define OFF_SPK2 34340864UL           // + 50*64*16*512
#define OFF_WT   85131264UL           // + 50*64*15872
#define OFF_PART 101384192UL          // + 496*32768 (wTf = 16252928 B, same as old wT)
#define OFF_COMB 127598592UL          // + 8*3200*256*4

typedef __attribute__((ext_vector_type(8))) short bf16x8;
typedef __attribute__((ext_vector_type(4))) float f32x4;

__device__ __forceinline__ uint32_t f32_to_bf16_rne(float f) {
  uint32_t u = __float_as_uint(f);
  return (u + 0x7FFFu + ((u >> 16) & 1u)) >> 16;
}

__device__ __forceinline__ void gload_lds16(const void* g, void* l) {
  __builtin_amdgcn_global_load_lds(
      (const __attribute__((address_space(1))) uint32_t*)g,
      (__attribute__((address_space(3))) uint32_t*)l, 16, 0, 0);
}

// ---------------- K1: fc1w [250,15776] -> wTf fragment-ready bf16 hi/lo ----------------
// layout: per k-tile kt (32 k's): [sel(hi/lo)][n(256)][kk(32)] bf16 -> 32 KB per tile
__global__ __launch_bounds__(256) void k_wt(const float* __restrict__ fc1w,
                                            uint32_t* __restrict__ wTf) {
  int kt = blockIdx.x;        // 0..495
  int n = threadIdx.x;        // 0..255
  uint32_t hibuf[16], lobuf[16];
#pragma unroll 4
  for (int p = 0; p < 16; ++p) {
    uint32_t h2 = 0, l2 = 0;
#pragma unroll
    for (int e = 0; e < 2; ++e) {
      int k = kt * 32 + p * 2 + e;
      int oc = k / L2PAD;
      int pos = k - oc * L2PAD;
      float w = 0.f;
      if (pos < L2 && n < NFC) w = fc1w[n * KREAL + oc * L2 + pos];
      uint32_t hb = f32_to_bf16_rne(w);
      float hf = __uint_as_float(hb << 16);
      uint32_t lb = f32_to_bf16_rne(w - hf);
      h2 |= hb << (16 * e);
      l2 |= lb << (16 * e);
    }
    hibuf[p] = h2;
    lobuf[p] = l2;
  }
  uint32_t* rh = wTf + ((size_t)(kt * 2 + 0) * 256 + n) * 16;
  uint32_t* rl = wTf + ((size_t)(kt * 2 + 1) * 256 + n) * 16;
#pragma unroll 4
  for (int p = 0; p < 16; ++p) rh[p] = hibuf[p];
#pragma unroll 4
  for (int p = 0; p < 16; ++p) rl[p] = lobuf[p];
}

// ---------------- K2: conv1 (K=80, stride4) + BN1 fold -> cur1 [64][16][1984] ----------------
__global__ __launch_bounds__(256) void k_conv1(const float* __restrict__ x1, const float* __restrict__ x2,
                                               const float* __restrict__ c1w, const float* __restrict__ c1b,
                                               const float* __restrict__ g, const float* __restrict__ bb,
                                               const float* __restrict__ mn, const float* __restrict__ vr,
                                               float* __restrict__ cur1) {
  __shared__ float xs[1104];
  int item = blockIdx.y;
  int pc = blockIdx.x;                 // 0..7
  int tid = threadIdx.x;
  const float* x = (item < 32 ? x1 : x2) + (item & 31) * 8000;
  int xoff = pc * 1024;
  for (int i = tid; i < 1100; i += 256) {
    int gi = xoff + i;
    xs[i] = (gi < 8000) ? x[gi] : 0.f;
  }
  __syncthreads();
  int p = pc * 256 + tid;
  bool pv = (p < L1);
  for (int c = 0; c < C1; ++c) {
    float s = g[c] / sqrtf(vr[c] + BN_EPS);
    float sh = (c1b[c] - mn[c]) * s + bb[c];
    const float* wr = c1w + c * 80;
    float acc = 0.f;
#pragma unroll 10
    for (int k = 0; k < 80; ++k) acc += wr[k] * xs[4 * tid + k];
    if (pv) cur1[(item * C1 + c) * L1P + p] = acc * s + sh;
  }
}

// ---------------- K3: LIF1 (all 50 steps) + maxpool4 -> pooled bytes [50][64][16][512] ----------------
__global__ __launch_bounds__(256) void k_lif1(const float* __restrict__ cur1,
                                              uint8_t* __restrict__ pooled) {
  int idx = blockIdx.x * 256 + threadIdx.x;
  if (idx >= NITEM * C1 * P4) return;
  int item = idx / (C1 * P4);
  int rem = idx - item * (C1 * P4);
  int c = rem / P4;
  int p4 = rem - c * P4;
  const float4 cv = *reinterpret_cast<const float4*>(cur1 + (item * C1 + c) * L1P + 4 * p4);
  float m0 = 0.f, m1 = 0.f, m2 = 0.f, m3 = 0.f;
  uint8_t* out = pooled + (item * C1 + c) * PPAD + p4;
  const int tstride = NITEM * C1 * PPAD;
  for (int t = 0; t < T_STEPS; ++t) {
    float r0 = (m0 > THR) ? 1.f : 0.f;
    float r1 = (m1 > THR) ? 1.f : 0.f;
    float r2 = (m2 > THR) ? 1.f : 0.f;
    float r3 = (m3 > THR) ? 1.f : 0.f;
    m0 = BETA * m0 + cv.x - r0;
    m1 = BETA * m1 + cv.y - r1;
    m2 = BETA * m2 + cv.z - r2;
    m3 = BETA * m3 + cv.w - r3;
    int spk = (m0 > THR) | (m1 > THR) | (m2 > THR) | (m3 > THR);
    out[t * tstride] = (uint8_t)spk;
  }
}

// ---------------- K4: conv2 + BN2 + LIF2 -> spk2 bytes [50*64][32][496] (u32 stores) ----------------
__global__ __launch_bounds__(512) void k_conv2(const uint8_t* __restrict__ pooled,
                                               const float* __restrict__ c2w, const float* __restrict__ c2b,
                                               const float* __restrict__ g, const float* __restrict__ bb,
                                               const float* __restrict__ mn, const float* __restrict__ vr,
                                               uint32_t* __restrict__ spk2) {
  __shared__ uint32_t pl[C1][132];
  int item = blockIdx.y;
  int pos0 = blockIdx.x * 64;
  int tid = threadIdx.x;
  int oc = tid >> 4;
  int pg = tid & 15;
  float s2 = g[oc] / sqrtf(vr[oc] + BN_EPS);
  float sh2 = (c2b[oc] - mn[oc]) * s2 + bb[oc];
  float w[48];
#pragma unroll
  for (int i = 0; i < 48; ++i) w[i] = c2w[oc * 48 + i] * s2;
  float mem0 = 0.f, mem1 = 0.f, mem2 = 0.f, mem3 = 0.f;
  int w0 = (pos0 >> 2) + pg;
  bool dostore = (pos0 + 4 * pg) < L2PAD;
  const uint32_t* gp = reinterpret_cast<const uint32_t*>(pooled) + item * (C1 * PPAD / 4);
  const int tstr = NITEM * C1 * PPAD / 4;
  int outbase = (item * KTOT + oc * L2PAD + pos0 + 4 * pg) >> 2;
  for (int t = 0; t < T_STEPS; ++t) {
    const uint32_t* gpt = gp + t * tstr;
    for (int i = tid; i < C1 * 128; i += 512) pl[i >> 7][i & 127] = gpt[i];
    __syncthreads();
    float c0 = sh2, c1v = sh2, c2v = sh2, c3v = sh2;
#pragma unroll
    for (int ic = 0; ic < C1; ++ic) {
      uint32_t wa = pl[ic][w0];
      uint32_t wb = pl[ic][w0 + 1];
      float f0 = (float)(wa & 0xffu);
      float f1 = (float)((wa >> 8) & 0xffu);
      float f2 = (float)((wa >> 16) & 0xffu);
      float f3 = (float)(wa >> 24);
      float f4 = (float)(wb & 0xffu);
      float f5 = (float)((wb >> 8) & 0xffu);
      float wk0 = w[ic * 3 + 0], wk1 = w[ic * 3 + 1], wk2 = w[ic * 3 + 2];
      c0 += wk0 * f0; c0 += wk1 * f1; c0 += wk2 * f2;
      c1v += wk0 * f1; c1v += wk1 * f2; c1v += wk2 * f3;
      c2v += wk0 * f2; c2v += wk1 * f3; c2v += wk2 * f4;
      c3v += wk0 * f3; c3v += wk1 * f4; c3v += wk2 * f5;
    }
    uint32_t packed = 0;
    {
      float r = (mem0 > THR) ? 1.f : 0.f; mem0 = BETA * mem0 + c0 - r;  if (mem0 > THR) packed |= 1u;
    }
    {
      float r = (mem1 > THR) ? 1.f : 0.f; mem1 = BETA * mem1 + c1v - r; if (mem1 > THR) packed |= (1u << 8);
    }
    {
      float r = (mem2 > THR) ? 1.f : 0.f; mem2 = BETA * mem2 + c2v - r; if (mem2 > THR) packed |= (1u << 16);
    }
    {
      float r = (mem3 > THR) ? 1.f : 0.f; mem3 = BETA * mem3 + c3v - r; if (mem3 > THR) packed |= (1u << 24);
    }
    if (dostore) spk2[t * (NITEM * KTOT / 4) + outbase] = packed;
    __syncthreads();
  }
}

// ---------------- K5: fc1 MFMA GEMM  part[ks][3200][256] += spk2[3200][KTOT] * (whi+wlo)[KTOT][256]
// tile: M=64, N=256, 4 waves (each wave 64x64), K-step 32, KSPLIT=8
__global__ __launch_bounds__(256) void k_fc1(const uint8_t* __restrict__ spk2,
                                             const uint8_t* __restrict__ wTf,
                                             float* __restrict__ part) {
  __shared__ __align__(16) uint8_t Al[64 * 64];          // [64 rows][32 bf16] = 4 KB
  __shared__ __align__(16) uint8_t Bl[2 * 256 * 64];     // [sel][256 n][32 bf16] = 32 KB
  int ks = blockIdx.x;
  int m0 = blockIdx.y * 64;
  int tid = threadIdx.x;
  int lane = tid & 63;
  int wv = tid >> 6;
  int r16 = lane & 15;
  int kg = lane >> 4;

  f32x4 acc[4][4];
#pragma unroll
  for (int mi = 0; mi < 4; ++mi)
#pragma unroll
    for (int ni = 0; ni < 4; ++ni) acc[mi][ni] = (f32x4){0.f, 0.f, 0.f, 0.f};

  const uint32_t* A32 = reinterpret_cast<const uint32_t*>(spk2);
  int arow = tid & 63;
  int akg = tid >> 6;                     // 0..3
  int abase = ((m0 + arow) * KTOT) >> 2;  // u32 index of A row start

  for (int ch = 0; ch < KSTEPS; ++ch) {
    int k0 = ks * KRANGE + ch * 32;
    // ---- stage A: 2 u32 (8 spike bytes) -> 4 u32 (8 bf16) -> one 16B LDS write
    uint32_t a0 = A32[abase + (k0 >> 2) + akg * 2];
    uint32_t a1 = A32[abase + (k0 >> 2) + akg * 2 + 1];
    uint32_t s0 = a0 & 0x01010101u, s1 = a1 & 0x01010101u;
    uint4 av;
    av.x = (s0 & 1u) * 0x3F80u | ((s0 >> 8) & 1u) * 0x3F800000u;
    av.y = ((s0 >> 16) & 1u) * 0x3F80u | ((s0 >> 24) & 1u) * 0x3F800000u;
    av.z = (s1 & 1u) * 0x3F80u | ((s1 >> 8) & 1u) * 0x3F800000u;
    av.w = ((s1 >> 16) & 1u) * 0x3F80u | ((s1 >> 24) & 1u) * 0x3F800000u;
    *reinterpret_cast<uint4*>(&Al[arow * 64 + akg * 16]) = av;
    // ---- stage B: 32 KB linear via global_load_lds (source is fragment-ready)
    const uint8_t* bsrc = wTf + (size_t)(ks * KSTEPS + ch) * 32768;
#pragma unroll
    for (int i = 0; i < 8; ++i) {
      int idx = i * 256 + tid;
      gload_lds16(bsrc + idx * 16, &Bl[idx * 16]);
    }
    __syncthreads();
    // ---- frags + MFMA
    bf16x8 af[4];
#pragma unroll
    for (int mi = 0; mi < 4; ++mi)
      af[mi] = *reinterpret_cast<const bf16x8*>(&Al[(mi * 16 + r16) * 64 + kg * 16]);
#pragma unroll
    for (int ni = 0; ni < 4; ++ni) {
      int nrow = wv * 64 + ni * 16 + r16;
      bf16x8 bh = *reinterpret_cast<const bf16x8*>(&Bl[nrow * 64 + kg * 16]);
      bf16x8 bl = *reinterpret_cast<const bf16x8*>(&Bl[16384 + nrow * 64 + kg * 16]);
#pragma unroll
      for (int mi = 0; mi < 4; ++mi) {
        acc[mi][ni] = __builtin_amdgcn_mfma_f32_16x16x32_bf16(af[mi], bh, acc[mi][ni], 0, 0, 0);
        acc[mi][ni] = __builtin_amdgcn_mfma_f32_16x16x32_bf16(af[mi], bl, acc[mi][ni], 0, 0, 0);
      }
    }
    __syncthreads();
  }
  // ---- epilogue: C/D layout col=lane&15, row=(lane>>4)*4+r (m89-verified)
  int colb = wv * 64 + r16;
  int rowb = m0 + kg * 4;
#pragma unroll
  for (int mi = 0; mi < 4; ++mi)
#pragma unroll
    for (int ni = 0; ni < 4; ++ni) {
      float* pp = part + (size_t)(ks * MROWS + rowb + mi * 16) * NPAD + colb + ni * 16;
#pragma unroll
      for (int r = 0; r < 4; ++r) pp[r * NPAD] = acc[mi][ni][r];
    }
}

// ---------------- K6: reduce K-splits + fc1 bias + LIF3 + rate/latency -> comb [64][500] ----------------
__global__ __launch_bounds__(256) void k_lif3(const float* __restrict__ part,
                                              const float* __restrict__ fc1b,
                                              float* __restrict__ comb) {
  int item = blockIdx.x;
  int n = threadIdx.x;
  if (n >= NFC) return;
  float mem = 0.f, cnt = 0.f;
  int first = -1;
  float bias = fc1b[n];
  for (int t = 0; t < T_STEPS; ++t) {
    int row = t * NITEM + item;
    float s = bias;
#pragma unroll
    for (int ksx = 0; ksx < KSPLIT; ++ksx) s += part[(ksx * MROWS + row) * NPAD + n];
    float r = (mem > THR) ? 1.f : 0.f;
    mem = BETA * mem + s - r;
    if (mem > THR) { cnt += 1.f; if (first < 0) first = t; }
  }
  comb[item * 500 + n] = cnt;
  comb[item * 500 + NFC + n] = (first < 0) ? 0.f : ((float)first / (float)T_STEPS);
}

// ---------------- K7: head GEMM [64]x[500]->[128] + L2 normalize -> d_out ----------------
__global__ __launch_bounds__(128) void k_head(const float* __restrict__ comb,
                                              const float* __restrict__ fcsw,
                                              const float* __restrict__ fcsb,
                                              float* __restrict__ dout) {
  __shared__ float cr[500];
  __shared__ float red[2];
  int item = blockIdx.x;
  int o = threadIdx.x;
  for (int i = o; i < 500; i += 128) cr[i] = comb[item * 500 + i];
  __syncthreads();
  float acc = fcsb[o];
  for (int j = 0; j < 500; ++j) acc += cr[j] * fcsw[o * 500 + j];
  float sq = acc * acc;
  for (int off = 32; off > 0; off >>= 1) sq += __shfl_down(sq, off, 64);
  if ((o & 63) == 0) red[o >> 6] = sq;
  __syncthreads();
  float norm = sqrtf(red[0] + red[1]);
  norm = fmaxf(norm, 1e-12f);
  dout[item * 128 + o] = acc / norm;
}

// ---------------- launch ----------------
extern "C" void kernel_launch(void* const* d_in, const int* in_sizes, int n_in,
                              void* d_out, int out_size, void* d_ws, size_t ws_size,
                              hipStream_t stream) {
  const float* x1   = (const float*)d_in[0];
  const float* x2   = (const float*)d_in[1];
  const float* c1w  = (const float*)d_in[2];
  const float* c1b  = (const float*)d_in[3];
  const float* bn1g = (const float*)d_in[4];
  const float* bn1b = (const float*)d_in[5];
  const float* bn1m = (const float*)d_in[6];
  const float* bn1v = (const float*)d_in[7];
  const float* c2w  = (const float*)d_in[8];
  const float* c2b  = (const float*)d_in[9];
  const float* bn2g = (const float*)d_in[10];
  const float* bn2b = (const float*)d_in[11];
  const float* bn2m = (const float*)d_in[12];
  const float* bn2v = (const float*)d_in[13];
  const float* fc1w = (const float*)d_in[14];
  const float* fc1b = (const float*)d_in[15];
  const float* fcsw = (const float*)d_in[16];
  const float* fcsb = (const float*)d_in[17];

  char* ws = (char*)d_ws;
  float*    cur1   = (float*)(ws + OFF_CUR1);
  uint8_t*  pooled = (uint8_t*)(ws + OFF_POOL);
  uint8_t*  spk2   = (uint8_t*)(ws + OFF_SPK2);
  uint8_t*  wTf    = (uint8_t*)(ws + OFF_WT);
  float*    part   = (float*)(ws + OFF_PART);
  float*    comb   = (float*)(ws + OFF_COMB);

  k_wt<<<dim3(NKTILE), dim3(256), 0, stream>>>(fc1w, (uint32_t*)wTf);
  k_conv1<<<dim3(8, NITEM), dim3(256), 0, stream>>>(x1, x2, c1w, c1b, bn1g, bn1b, bn1m, bn1v, cur1);
  k_lif1<<<dim3((NITEM * C1 * P4 + 255) / 256), dim3(256), 0, stream>>>(cur1, pooled);
  k_conv2<<<dim3(8, NITEM), dim3(512), 0, stream>>>(pooled, c2w, c2b, bn2g, bn2b, bn2m, bn2v,
                                                    (uint32_t*)spk2);
  k_fc1<<<dim3(KSPLIT, MROWS / 64), dim3(256), 0, stream>>>(spk2, wTf, part);
  k_lif3<<<dim3(NITEM), dim3(256), 0, stream>>>(part, fc1b, comb);
  k_head<<<dim3(NITEM), dim3(128), 0, stream>>>(comb, fcsw, fcsb, (float*)d_out);
}

// Round 3
// 253.322 us; speedup vs baseline: 2.9600x; 1.6057x over previous
//
#include <hip/hip_runtime.h>
#include <math.h>
#include <stdint.h>

// ---------------- dims ----------------
#define BETA 0.9f
#define THR 1.0f
#define T_STEPS 50
#define BN_EPS 1e-5f

#define NITEM 64          // 2 inputs x 32 batch
#define C1 16
#define L1 1981           // conv1 out length
#define L1P 1984          // padded
#define P4 495            // pooled length
#define C2 32
#define L2 493            // conv2 out length
#define L2PAD 496
#define KTOT 15872        // C2*L2PAD (padded flat dim)
#define KREAL 15776       // C2*L2
#define NFC 250
#define NPAD 256
#define KSPLIT 8
#define KRANGE 1984       // KTOT/KSPLIT
#define KSTEPS 62         // KRANGE/32
#define NKTILE 496        // KTOT/32
#define MROWS 3200        // T_STEPS*NITEM

// ---------------- workspace layout (bytes) ----------------
// pooled_T now: [item][t][512 pos][16 ic] bytes = 64*50*8192 = 26214400 (same size as before)
#define OFF_CUR1 0UL
#define OFF_POOL 8126464UL            // 64*16*1984*4
#define OFF_SPK2 34340864UL           // + 26214400
#define OFF_WT   85131264UL           // + 50*64*15872
#define OFF_PART 101384192UL          // + 496*32768 (wTf = 16252928 B)
#define OFF_COMB 127598592UL          // + 8*3200*256*4
// conv2 weight frags (8KB + 128B sh2) reuse the cur1 region (dead after k_lif1)

typedef __attribute__((ext_vector_type(8))) short bf16x8;
typedef __attribute__((ext_vector_type(4))) float f32x4;

__device__ __forceinline__ uint32_t f32_to_bf16_rne(float f) {
  uint32_t u = __float_as_uint(f);
  return (u + 0x7FFFu + ((u >> 16) & 1u)) >> 16;
}

__device__ __forceinline__ void gload_lds16(const void* g, void* l) {
  __builtin_amdgcn_global_load_lds(
      (const __attribute__((address_space(1))) uint32_t*)g,
      (__attribute__((address_space(3))) uint32_t*)l, 16, 0, 0);
}

// spike bytes (bit0) -> 8 bf16 {0,1}
__device__ __forceinline__ bf16x8 frag_from_bytes(uint2 a) {
  union { uint32_t u[4]; bf16x8 v; } c;
  c.u[0] = (a.x & 1u) * 0x3F80u | ((a.x >> 8) & 1u) * 0x3F800000u;
  c.u[1] = ((a.x >> 16) & 1u) * 0x3F80u | ((a.x >> 24) & 1u) * 0x3F800000u;
  c.u[2] = (a.y & 1u) * 0x3F80u | ((a.y >> 8) & 1u) * 0x3F800000u;
  c.u[3] = ((a.y >> 16) & 1u) * 0x3F80u | ((a.y >> 24) & 1u) * 0x3F800000u;
  return c.v;
}

// ---------------- K1: fc1w [250,15776] -> wTf fragment-ready bf16 hi/lo ----------------
__global__ __launch_bounds__(256) void k_wt(const float* __restrict__ fc1w,
                                            uint32_t* __restrict__ wTf) {
  int kt = blockIdx.x;        // 0..495
  int n = threadIdx.x;        // 0..255
  uint32_t hibuf[16], lobuf[16];
#pragma unroll 4
  for (int p = 0; p < 16; ++p) {
    uint32_t h2 = 0, l2 = 0;
#pragma unroll
    for (int e = 0; e < 2; ++e) {
      int k = kt * 32 + p * 2 + e;
      int oc = k / L2PAD;
      int pos = k - oc * L2PAD;
      float w = 0.f;
      if (pos < L2 && n < NFC) w = fc1w[n * KREAL + oc * L2 + pos];
      uint32_t hb = f32_to_bf16_rne(w);
      float hf = __uint_as_float(hb << 16);
      uint32_t lb = f32_to_bf16_rne(w - hf);
      h2 |= hb << (16 * e);
      l2 |= lb << (16 * e);
    }
    hibuf[p] = h2;
    lobuf[p] = l2;
  }
  uint32_t* rh = wTf + ((size_t)(kt * 2 + 0) * 256 + n) * 16;
  uint32_t* rl = wTf + ((size_t)(kt * 2 + 1) * 256 + n) * 16;
#pragma unroll 4
  for (int p = 0; p < 16; ++p) rh[p] = hibuf[p];
#pragma unroll 4
  for (int p = 0; p < 16; ++p) rl[p] = lobuf[p];
}

// ---------------- K2: conv1 (K=80, stride4) + BN1 fold -> cur1 [64][16][1984] ----------------
__global__ __launch_bounds__(256) void k_conv1(const float* __restrict__ x1, const float* __restrict__ x2,
                                               const float* __restrict__ c1w, const float* __restrict__ c1b,
                                               const float* __restrict__ g, const float* __restrict__ bb,
                                               const float* __restrict__ mn, const float* __restrict__ vr,
                                               float* __restrict__ cur1) {
  __shared__ float xs[1104];
  int item = blockIdx.y;
  int pc = blockIdx.x;                 // 0..7
  int tid = threadIdx.x;
  const float* x = (item < 32 ? x1 : x2) + (item & 31) * 8000;
  int xoff = pc * 1024;
  for (int i = tid; i < 1100; i += 256) {
    int gi = xoff + i;
    xs[i] = (gi < 8000) ? x[gi] : 0.f;
  }
  __syncthreads();
  int p = pc * 256 + tid;
  bool pv = (p < L1);
  for (int c = 0; c < C1; ++c) {
    float s = g[c] / sqrtf(vr[c] + BN_EPS);
    float sh = (c1b[c] - mn[c]) * s + bb[c];
    const float* wr = c1w + c * 80;
    float acc = 0.f;
#pragma unroll 10
    for (int k = 0; k < 80; ++k) acc += wr[k] * xs[4 * tid + k];
    if (pv) cur1[(item * C1 + c) * L1P + p] = acc * s + sh;
  }
}

// ---------------- K3: LIF1 (all 50 steps) + maxpool4 -> pooled_T [item][t][512][16] bytes ----------------
__global__ __launch_bounds__(256) void k_lif1(const float* __restrict__ cur1,
                                              uint8_t* __restrict__ pooledT) {
  int idx = blockIdx.x * 256 + threadIdx.x;
  if (idx >= NITEM * C1 * P4) return;
  int item = idx / (C1 * P4);
  int rem = idx - item * (C1 * P4);
  int c = rem / P4;
  int p4 = rem - c * P4;
  const float4 cv = *reinterpret_cast<const float4*>(cur1 + (item * C1 + c) * L1P + 4 * p4);
  float m0 = 0.f, m1 = 0.f, m2 = 0.f, m3 = 0.f;
  uint8_t* out = pooledT + ((size_t)item * 50 * 512 + p4) * 16 + c;
  for (int t = 0; t < T_STEPS; ++t) {
    float r0 = (m0 > THR) ? 1.f : 0.f;
    float r1 = (m1 > THR) ? 1.f : 0.f;
    float r2 = (m2 > THR) ? 1.f : 0.f;
    float r3 = (m3 > THR) ? 1.f : 0.f;
    m0 = BETA * m0 + cv.x - r0;
    m1 = BETA * m1 + cv.y - r1;
    m2 = BETA * m2 + cv.z - r2;
    m3 = BETA * m3 + cv.w - r3;
    int spk = (m0 > THR) | (m1 > THR) | (m2 > THR) | (m3 > THR);
    out[t * 8192] = (uint8_t)spk;
  }
}

// ---------------- K3b: conv2 weight frags (hi/lo, BN-folded) + sh2 -> wfrag (cur1 region) ----------------
// frag fr = nt*4 + kt*2 + hl : [64 lanes][8 bf16]; k = kt*32 + kg*8 + j; tap=k>>4, ic=k&15 (tap>=3 -> 0)
__global__ __launch_bounds__(512) void k_wc2(const float* __restrict__ c2w, const float* __restrict__ c2b,
                                             const float* __restrict__ g, const float* __restrict__ bb,
                                             const float* __restrict__ mn, const float* __restrict__ vr,
                                             uint8_t* __restrict__ wfrag) {
  int t = threadIdx.x;
  int lane = t & 63;
  int fr = t >> 6;
  int hl = fr & 1, kt = (fr >> 1) & 1, nt = fr >> 2;
  int n16 = lane & 15, kg = lane >> 4;
  int oc = nt * 16 + n16;
  float s2 = g[oc] * rsqrtf(vr[oc] + BN_EPS);
  uint32_t w[4];
#pragma unroll
  for (int i = 0; i < 4; ++i) {
    uint32_t packed = 0;
#pragma unroll
    for (int e = 0; e < 2; ++e) {
      int j = i * 2 + e;
      int k = kt * 32 + kg * 8 + j;
      int tap = k >> 4, ic = k & 15;
      float raw = (tap < 3) ? c2w[oc * 48 + ic * 3 + tap] * s2 : 0.f;
      uint32_t hb = f32_to_bf16_rne(raw);
      float hf = __uint_as_float(hb << 16);
      uint32_t lb = f32_to_bf16_rne(raw - hf);
      uint32_t v = hl ? lb : hb;
      packed |= v << (16 * e);
    }
    w[i] = packed;
  }
  uint4 uu; uu.x = w[0]; uu.y = w[1]; uu.z = w[2]; uu.w = w[3];
  *reinterpret_cast<uint4*>(wfrag + fr * 1024 + lane * 16) = uu;
  if (t < C2) {
    float s2b = g[t] * rsqrtf(vr[t] + BN_EPS);
    reinterpret_cast<float*>(wfrag + 8192)[t] = (c2b[t] - mn[t]) * s2b + bb[t];
  }
}

// ---------------- K4: conv2 via MFMA + LIF2 (mem in acc lanes) -> spk2 bytes ----------------
// grid (8 pos-tiles, 64 items), 256 threads = 4 waves x 16 positions each
__global__ __launch_bounds__(256) void k_conv2(const uint8_t* __restrict__ pooledT,
                                               const uint8_t* __restrict__ wfrag,
                                               uint32_t* __restrict__ spk2) {
  int item = blockIdx.y;
  int pt = blockIdx.x;
  int tid = threadIdx.x;
  int lane = tid & 63, wv = tid >> 6;
  int r16 = lane & 15, kg = lane >> 4;
  bf16x8 bw[2][2][2];
#pragma unroll
  for (int nt = 0; nt < 2; ++nt)
#pragma unroll
    for (int kt = 0; kt < 2; ++kt)
#pragma unroll
      for (int hl = 0; hl < 2; ++hl)
        bw[nt][kt][hl] = *reinterpret_cast<const bf16x8*>(wfrag + (nt * 4 + kt * 2 + hl) * 1024 + lane * 16);
  float sh[2];
  sh[0] = reinterpret_cast<const float*>(wfrag + 8192)[r16];
  sh[1] = reinterpret_cast<const float*>(wfrag + 8192)[16 + r16];
  const uint8_t* base = pooledT + (size_t)item * 50 * 8192;
  int rowA = pt * 64 + wv * 16 + r16;                 // position this lane's A-row starts at
  size_t off0 = (size_t)(rowA + (kg >> 1)) * 16 + 8 * (kg & 1);   // taps 0/1
  size_t off1 = (size_t)(rowA + 2) * 16 + 8 * (kg & 1);           // tap 2 (+pad)
  uint2 na0 = *reinterpret_cast<const uint2*>(base + off0);
  uint2 na1 = *reinterpret_cast<const uint2*>(base + off1);
  float mem[2][4] = {{0.f, 0.f, 0.f, 0.f}, {0.f, 0.f, 0.f, 0.f}};
  int pos_base = pt * 64 + wv * 16 + kg * 4;          // C/D rows this lane owns
  bool dostore = pos_base < L2PAD;
  for (int t = 0; t < T_STEPS; ++t) {
    uint2 a0 = na0, a1 = na1;
    const uint8_t* nb = base + (size_t)((t + 1 < T_STEPS) ? t + 1 : t) * 8192;
    na0 = *reinterpret_cast<const uint2*>(nb + off0);
    na1 = *reinterpret_cast<const uint2*>(nb + off1);
    bf16x8 af0 = frag_from_bytes(a0);
    bf16x8 af1 = frag_from_bytes(a1);
    uint32_t st[2];
#pragma unroll
    for (int nt = 0; nt < 2; ++nt) {
      f32x4 acc = (f32x4){0.f, 0.f, 0.f, 0.f};
      acc = __builtin_amdgcn_mfma_f32_16x16x32_bf16(af0, bw[nt][0][0], acc, 0, 0, 0);
      acc = __builtin_amdgcn_mfma_f32_16x16x32_bf16(af1, bw[nt][1][0], acc, 0, 0, 0);
      acc = __builtin_amdgcn_mfma_f32_16x16x32_bf16(af0, bw[nt][0][1], acc, 0, 0, 0);
      acc = __builtin_amdgcn_mfma_f32_16x16x32_bf16(af1, bw[nt][1][1], acc, 0, 0, 0);
      uint32_t packed = 0;
#pragma unroll
      for (int r = 0; r < 4; ++r) {
        float rst = (mem[nt][r] > THR) ? 1.f : 0.f;
        mem[nt][r] = BETA * mem[nt][r] + (acc[r] + sh[nt]) - rst;
        packed |= (mem[nt][r] > THR ? 1u : 0u) << (8 * r);
      }
      st[nt] = packed;
    }
    if (dostore) {
      uint32_t idx0 = (uint32_t)(t * 64 + item) * (KTOT / 4) + r16 * (L2PAD / 4) + (pos_base >> 2);
      spk2[idx0] = st[0];
      spk2[idx0 + 16 * (L2PAD / 4)] = st[1];
    }
  }
}

// ---------------- K5: fc1 MFMA GEMM  part[ks][3200][256] += spk2[3200][KTOT] * (whi+wlo)[KTOT][256]
__global__ __launch_bounds__(256) void k_fc1(const uint8_t* __restrict__ spk2,
                                             const uint8_t* __restrict__ wTf,
                                             float* __restrict__ part) {
  __shared__ __align__(16) uint8_t Al[64 * 64];          // [64 rows][32 bf16] = 4 KB
  __shared__ __align__(16) uint8_t Bl[2 * 256 * 64];     // [sel][256 n][32 bf16] = 32 KB
  int ks = blockIdx.x;
  int m0 = blockIdx.y * 64;
  int tid = threadIdx.x;
  int lane = tid & 63;
  int wv = tid >> 6;
  int r16 = lane & 15;
  int kg = lane >> 4;

  f32x4 acc[4][4];
#pragma unroll
  for (int mi = 0; mi < 4; ++mi)
#pragma unroll
    for (int ni = 0; ni < 4; ++ni) acc[mi][ni] = (f32x4){0.f, 0.f, 0.f, 0.f};

  const uint32_t* A32 = reinterpret_cast<const uint32_t*>(spk2);
  int arow = tid & 63;
  int akg = tid >> 6;                     // 0..3
  int abase = ((m0 + arow) * KTOT) >> 2;  // u32 index of A row start

  for (int ch = 0; ch < KSTEPS; ++ch) {
    int k0 = ks * KRANGE + ch * 32;
    uint32_t a0 = A32[abase + (k0 >> 2) + akg * 2];
    uint32_t a1 = A32[abase + (k0 >> 2) + akg * 2 + 1];
    uint32_t s0 = a0 & 0x01010101u, s1 = a1 & 0x01010101u;
    uint4 av;
    av.x = (s0 & 1u) * 0x3F80u | ((s0 >> 8) & 1u) * 0x3F800000u;
    av.y = ((s0 >> 16) & 1u) * 0x3F80u | ((s0 >> 24) & 1u) * 0x3F800000u;
    av.z = (s1 & 1u) * 0x3F80u | ((s1 >> 8) & 1u) * 0x3F800000u;
    av.w = ((s1 >> 16) & 1u) * 0x3F80u | ((s1 >> 24) & 1u) * 0x3F800000u;
    *reinterpret_cast<uint4*>(&Al[arow * 64 + akg * 16]) = av;
    const uint8_t* bsrc = wTf + (size_t)(ks * KSTEPS + ch) * 32768;
#pragma unroll
    for (int i = 0; i < 8; ++i) {
      int idx = i * 256 + tid;
      gload_lds16(bsrc + idx * 16, &Bl[idx * 16]);
    }
    __syncthreads();
    bf16x8 af[4];
#pragma unroll
    for (int mi = 0; mi < 4; ++mi)
      af[mi] = *reinterpret_cast<const bf16x8*>(&Al[(mi * 16 + r16) * 64 + kg * 16]);
#pragma unroll
    for (int ni = 0; ni < 4; ++ni) {
      int nrow = wv * 64 + ni * 16 + r16;
      bf16x8 bh = *reinterpret_cast<const bf16x8*>(&Bl[nrow * 64 + kg * 16]);
      bf16x8 bl = *reinterpret_cast<const bf16x8*>(&Bl[16384 + nrow * 64 + kg * 16]);
#pragma unroll
      for (int mi = 0; mi < 4; ++mi) {
        acc[mi][ni] = __builtin_amdgcn_mfma_f32_16x16x32_bf16(af[mi], bh, acc[mi][ni], 0, 0, 0);
        acc[mi][ni] = __builtin_amdgcn_mfma_f32_16x16x32_bf16(af[mi], bl, acc[mi][ni], 0, 0, 0);
      }
    }
    __syncthreads();
  }
  int colb = wv * 64 + r16;
  int rowb = m0 + kg * 4;
#pragma unroll
  for (int mi = 0; mi < 4; ++mi)
#pragma unroll
    for (int ni = 0; ni < 4; ++ni) {
      float* pp = part + (size_t)(ks * MROWS + rowb + mi * 16) * NPAD + colb + ni * 16;
#pragma unroll
      for (int r = 0; r < 4; ++r) pp[r * NPAD] = acc[mi][ni][r];
    }
}

// ---------------- K6: reduce K-splits + fc1 bias + LIF3 + rate/latency -> comb [64][500] ----------------
__global__ __launch_bounds__(256) void k_lif3(const float* __restrict__ part,
                                              const float* __restrict__ fc1b,
                                              float* __restrict__ comb) {
  int item = blockIdx.x;
  int n = threadIdx.x;
  if (n >= NFC) return;
  float mem = 0.f, cnt = 0.f;
  int first = -1;
  float bias = fc1b[n];
  for (int t = 0; t < T_STEPS; ++t) {
    int row = t * NITEM + item;
    float s = bias;
#pragma unroll
    for (int ksx = 0; ksx < KSPLIT; ++ksx) s += part[(ksx * MROWS + row) * NPAD + n];
    float r = (mem > THR) ? 1.f : 0.f;
    mem = BETA * mem + s - r;
    if (mem > THR) { cnt += 1.f; if (first < 0) first = t; }
  }
  comb[item * 500 + n] = cnt;
  comb[item * 500 + NFC + n] = (first < 0) ? 0.f : ((float)first / (float)T_STEPS);
}

// ---------------- K7: head GEMM [64]x[500]->[128] + L2 normalize -> d_out ----------------
__global__ __launch_bounds__(128) void k_head(const float* __restrict__ comb,
                                              const float* __restrict__ fcsw,
                                              const float* __restrict__ fcsb,
                                              float* __restrict__ dout) {
  __shared__ float cr[500];
  __shared__ float red[2];
  int item = blockIdx.x;
  int o = threadIdx.x;
  for (int i = o; i < 500; i += 128) cr[i] = comb[item * 500 + i];
  __syncthreads();
  float acc = fcsb[o];
  for (int j = 0; j < 500; ++j) acc += cr[j] * fcsw[o * 500 + j];
  float sq = acc * acc;
  for (int off = 32; off > 0; off >>= 1) sq += __shfl_down(sq, off, 64);
  if ((o & 63) == 0) red[o >> 6] = sq;
  __syncthreads();
  float norm = sqrtf(red[0] + red[1]);
  norm = fmaxf(norm, 1e-12f);
  dout[item * 128 + o] = acc / norm;
}

// ---------------- launch ----------------
extern "C" void kernel_launch(void* const* d_in, const int* in_sizes, int n_in,
                              void* d_out, int out_size, void* d_ws, size_t ws_size,
                              hipStream_t stream) {
  const float* x1   = (const float*)d_in[0];
  const float* x2   = (const float*)d_in[1];
  const float* c1w  = (const float*)d_in[2];
  const float* c1b  = (const float*)d_in[3];
  const float* bn1g = (const float*)d_in[4];
  const float* bn1b = (const float*)d_in[5];
  const float* bn1m = (const float*)d_in[6];
  const float* bn1v = (const float*)d_in[7];
  const float* c2w  = (const float*)d_in[8];
  const float* c2b  = (const float*)d_in[9];
  const float* bn2g = (const float*)d_in[10];
  const float* bn2b = (const float*)d_in[11];
  const float* bn2m = (const float*)d_in[12];
  const float* bn2v = (const float*)d_in[13];
  const float* fc1w = (const float*)d_in[14];
  const float* fc1b = (const float*)d_in[15];
  const float* fcsw = (const float*)d_in[16];
  const float* fcsb = (const float*)d_in[17];

  char* ws = (char*)d_ws;
  float*    cur1    = (float*)(ws + OFF_CUR1);
  uint8_t*  wfrag   = (uint8_t*)(ws + OFF_CUR1);   // reused AFTER k_lif1
  uint8_t*  pooledT = (uint8_t*)(ws + OFF_POOL);
  uint8_t*  spk2    = (uint8_t*)(ws + OFF_SPK2);
  uint8_t*  wTf     = (uint8_t*)(ws + OFF_WT);
  float*    part    = (float*)(ws + OFF_PART);
  float*    comb    = (float*)(ws + OFF_COMB);

  k_wt<<<dim3(NKTILE), dim3(256), 0, stream>>>(fc1w, (uint32_t*)wTf);
  k_conv1<<<dim3(8, NITEM), dim3(256), 0, stream>>>(x1, x2, c1w, c1b, bn1g, bn1b, bn1m, bn1v, cur1);
  k_lif1<<<dim3((NITEM * C1 * P4 + 255) / 256), dim3(256), 0, stream>>>(cur1, pooledT);
  k_wc2<<<dim3(1), dim3(512), 0, stream>>>(c2w, c2b, bn2g, bn2b, bn2m, bn2v, wfrag);
  k_conv2<<<dim3(8, NITEM), dim3(256), 0, stream>>>(pooledT, wfrag, (uint32_t*)spk2);
  k_fc1<<<dim3(KSPLIT, MROWS / 64), dim3(256), 0, stream>>>(spk2, wTf, part);
  k_lif3<<<dim3(NITEM), dim3(256), 0, stream>>>(part, fc1b, comb);
  k_head<<<dim3(NITEM), dim3(128), 0, stream>>>(comb, fcsw, fcsb, (float*)d_out);
}

// Round 4
// 231.548 us; speedup vs baseline: 3.2384x; 1.0940x over previous
//
#include <hip/hip_runtime.h>
#include <math.h>
#include <stdint.h>

// ---------------- dims ----------------
#define BETA 0.9f
#define THR 1.0f
#define T_STEPS 50
#define BN_EPS 1e-5f

#define NITEM 64          // 2 inputs x 32 batch
#define C1 16
#define L1 1981           // conv1 out length
#define L1P 1984          // padded
#define P4 495            // pooled length
#define C2 32
#define L2 493            // conv2 out length
#define L2PAD 496
#define KTOT 15872        // C2*L2PAD (padded flat dim)
#define KREAL 15776       // C2*L2
#define NFC 250
#define NPAD 256
#define KSPLIT 8
#define KRANGE 1984       // KTOT/KSPLIT
#define KSTEPS 62         // KRANGE/32
#define NKTILE 496        // KTOT/32
#define MROWS 3200        // T_STEPS*NITEM

// ---------------- workspace layout (bytes) ----------------
// pooled_T: [item][t][512 pos][16 ic] bytes = 64*50*8192 = 26214400
#define OFF_CUR1 0UL
#define OFF_POOL 8126464UL            // 64*16*1984*4
#define OFF_SPK2 34340864UL           // + 26214400
#define OFF_WT   85131264UL           // + 50*64*15872
#define OFF_PART 101384192UL          // + 496*32768 (wTf = 16252928 B)
#define OFF_COMB 127598592UL          // + 8*3200*256*4
// conv2 weight frags (8KB + 128B sh2) reuse the cur1 region (dead after k_lif1)

typedef __attribute__((ext_vector_type(8))) short bf16x8;
typedef __attribute__((ext_vector_type(4))) float f32x4;

__device__ __forceinline__ uint32_t f32_to_bf16_rne(float f) {
  uint32_t u = __float_as_uint(f);
  return (u + 0x7FFFu + ((u >> 16) & 1u)) >> 16;
}

// spike bytes (bit0) -> 8 bf16 {0,1}
__device__ __forceinline__ bf16x8 frag_from_bytes(uint2 a) {
  union { uint32_t u[4]; bf16x8 v; } c;
  c.u[0] = (a.x & 1u) * 0x3F80u | ((a.x >> 8) & 1u) * 0x3F800000u;
  c.u[1] = ((a.x >> 16) & 1u) * 0x3F80u | ((a.x >> 24) & 1u) * 0x3F800000u;
  c.u[2] = (a.y & 1u) * 0x3F80u | ((a.y >> 8) & 1u) * 0x3F800000u;
  c.u[3] = ((a.y >> 16) & 1u) * 0x3F80u | ((a.y >> 24) & 1u) * 0x3F800000u;
  return c.v;
}

// ---------------- K1: fc1w [250,15776] -> wTf wave-fragment-ready bf16 hi/lo ----------------
// per k-tile (32 k's): [wv(4)][ni(4)][sel(2)][lane(64)][16B] = 32 KB
// frag lane l = kg*16 + r16 holds n = wv*64+ni*16+r16, k-slice kg*8..+8
__global__ __launch_bounds__(256) void k_wt(const float* __restrict__ fc1w,
                                            uint8_t* __restrict__ wTf) {
  int kt = blockIdx.x;        // 0..495
  int n = threadIdx.x;        // 0..255
  int wv = n >> 6, ni = (n >> 4) & 3, r16 = n & 15;
  uint32_t hibuf[16], lobuf[16];
#pragma unroll 4
  for (int p = 0; p < 16; ++p) {
    uint32_t h2 = 0, l2 = 0;
#pragma unroll
    for (int e = 0; e < 2; ++e) {
      int k = kt * 32 + p * 2 + e;
      int oc = k / L2PAD;
      int pos = k - oc * L2PAD;
      float w = 0.f;
      if (pos < L2 && n < NFC) w = fc1w[n * KREAL + oc * L2 + pos];
      uint32_t hb = f32_to_bf16_rne(w);
      float hf = __uint_as_float(hb << 16);
      uint32_t lb = f32_to_bf16_rne(w - hf);
      h2 |= hb << (16 * e);
      l2 |= lb << (16 * e);
    }
    hibuf[p] = h2;
    lobuf[p] = l2;
  }
  uint8_t* tb = wTf + (size_t)kt * 32768 + wv * 8192 + ni * 2048;
#pragma unroll
  for (int kgi = 0; kgi < 4; ++kgi) {
    uint4 h; h.x = hibuf[4 * kgi]; h.y = hibuf[4 * kgi + 1]; h.z = hibuf[4 * kgi + 2]; h.w = hibuf[4 * kgi + 3];
    *reinterpret_cast<uint4*>(tb + (kgi * 16 + r16) * 16) = h;
    uint4 l; l.x = lobuf[4 * kgi]; l.y = lobuf[4 * kgi + 1]; l.z = lobuf[4 * kgi + 2]; l.w = lobuf[4 * kgi + 3];
    *reinterpret_cast<uint4*>(tb + 1024 + (kgi * 16 + r16) * 16) = l;
  }
}

// ---------------- K2: conv1 (K=80, stride4) + BN1 fold -> cur1 [64][16][1984] ----------------
__global__ __launch_bounds__(256) void k_conv1(const float* __restrict__ x1, const float* __restrict__ x2,
                                               const float* __restrict__ c1w, const float* __restrict__ c1b,
                                               const float* __restrict__ g, const float* __restrict__ bb,
                                               const float* __restrict__ mn, const float* __restrict__ vr,
                                               float* __restrict__ cur1) {
  __shared__ float xs[1104];
  int item = blockIdx.y;
  int pc = blockIdx.x;                 // 0..7
  int tid = threadIdx.x;
  const float* x = (item < 32 ? x1 : x2) + (item & 31) * 8000;
  int xoff = pc * 1024;
  for (int i = tid; i < 1100; i += 256) {
    int gi = xoff + i;
    xs[i] = (gi < 8000) ? x[gi] : 0.f;
  }
  __syncthreads();
  int p = pc * 256 + tid;
  bool pv = (p < L1);
  for (int c = 0; c < C1; ++c) {
    float s = g[c] / sqrtf(vr[c] + BN_EPS);
    float sh = (c1b[c] - mn[c]) * s + bb[c];
    const float* wr = c1w + c * 80;
    float acc = 0.f;
#pragma unroll 10
    for (int k = 0; k < 80; ++k) acc += wr[k] * xs[4 * tid + k];
    if (pv) cur1[(item * C1 + c) * L1P + p] = acc * s + sh;
  }
}

// ---------------- K3: LIF1 + maxpool4, coalesced u32 stores -> pooled_T [item][t][512][16] ----------------
// thread = (item, p4, g): 4 channels c=4g..4g+3, 4 pool lanes each; packs 4 spike bytes -> u32
__global__ __launch_bounds__(256) void k_lif1(const float* __restrict__ cur1,
                                              uint8_t* __restrict__ pooledT) {
  int item = blockIdx.y;
  int g = threadIdx.x & 3;
  int p4 = blockIdx.x * 64 + (threadIdx.x >> 2);
  if (p4 >= P4) return;
  float4 cv[4];
#pragma unroll
  for (int j = 0; j < 4; ++j)
    cv[j] = *reinterpret_cast<const float4*>(cur1 + ((size_t)item * C1 + g * 4 + j) * L1P + 4 * p4);
  float m[4][4];
#pragma unroll
  for (int j = 0; j < 4; ++j)
#pragma unroll
    for (int r = 0; r < 4; ++r) m[j][r] = 0.f;
  uint32_t* out = reinterpret_cast<uint32_t*>(pooledT + ((size_t)item * 50 * 512 + p4) * 16 + g * 4);
  for (int t = 0; t < T_STEPS; ++t) {
    uint32_t pk = 0;
#pragma unroll
    for (int j = 0; j < 4; ++j) {
      int s = 0;
#pragma unroll
      for (int r = 0; r < 4; ++r) {
        float rst = (m[j][r] > THR) ? 1.f : 0.f;
        float cvv = (r == 0) ? cv[j].x : (r == 1) ? cv[j].y : (r == 2) ? cv[j].z : cv[j].w;
        m[j][r] = BETA * m[j][r] + cvv - rst;
        s |= (m[j][r] > THR);
      }
      pk |= ((uint32_t)s) << (8 * j);
    }
    out[t * 2048] = pk;
  }
}

// ---------------- K3b: conv2 weight frags (hi/lo, BN-folded) + sh2 -> wfrag (cur1 region) ----------------
__global__ __launch_bounds__(512) void k_wc2(const float* __restrict__ c2w, const float* __restrict__ c2b,
                                             const float* __restrict__ g, const float* __restrict__ bb,
                                             const float* __restrict__ mn, const float* __restrict__ vr,
                                             uint8_t* __restrict__ wfrag) {
  int t = threadIdx.x;
  int lane = t & 63;
  int fr = t >> 6;
  int hl = fr & 1, kt = (fr >> 1) & 1, nt = fr >> 2;
  int n16 = lane & 15, kg = lane >> 4;
  int oc = nt * 16 + n16;
  float s2 = g[oc] * rsqrtf(vr[oc] + BN_EPS);
  uint32_t w[4];
#pragma unroll
  for (int i = 0; i < 4; ++i) {
    uint32_t packed = 0;
#pragma unroll
    for (int e = 0; e < 2; ++e) {
      int j = i * 2 + e;
      int k = kt * 32 + kg * 8 + j;
      int tap = k >> 4, ic = k & 15;
      float raw = (tap < 3) ? c2w[oc * 48 + ic * 3 + tap] * s2 : 0.f;
      uint32_t hb = f32_to_bf16_rne(raw);
      float hf = __uint_as_float(hb << 16);
      uint32_t lb = f32_to_bf16_rne(raw - hf);
      uint32_t v = hl ? lb : hb;
      packed |= v << (16 * e);
    }
    w[i] = packed;
  }
  uint4 uu; uu.x = w[0]; uu.y = w[1]; uu.z = w[2]; uu.w = w[3];
  *reinterpret_cast<uint4*>(wfrag + fr * 1024 + lane * 16) = uu;
  if (t < C2) {
    float s2b = g[t] * rsqrtf(vr[t] + BN_EPS);
    reinterpret_cast<float*>(wfrag + 8192)[t] = (c2b[t] - mn[t]) * s2b + bb[t];
  }
}

// ---------------- K4: conv2 via MFMA + LIF2 (mem in acc lanes) -> spk2 bytes ----------------
__global__ __launch_bounds__(256) void k_conv2(const uint8_t* __restrict__ pooledT,
                                               const uint8_t* __restrict__ wfrag,
                                               uint32_t* __restrict__ spk2) {
  int item = blockIdx.y;
  int pt = blockIdx.x;
  int tid = threadIdx.x;
  int lane = tid & 63, wv = tid >> 6;
  int r16 = lane & 15, kg = lane >> 4;
  bf16x8 bw[2][2][2];
#pragma unroll
  for (int nt = 0; nt < 2; ++nt)
#pragma unroll
    for (int kt = 0; kt < 2; ++kt)
#pragma unroll
      for (int hl = 0; hl < 2; ++hl)
        bw[nt][kt][hl] = *reinterpret_cast<const bf16x8*>(wfrag + (nt * 4 + kt * 2 + hl) * 1024 + lane * 16);
  float sh[2];
  sh[0] = reinterpret_cast<const float*>(wfrag + 8192)[r16];
  sh[1] = reinterpret_cast<const float*>(wfrag + 8192)[16 + r16];
  const uint8_t* base = pooledT + (size_t)item * 50 * 8192;
  int rowA = pt * 64 + wv * 16 + r16;
  size_t off0 = (size_t)(rowA + (kg >> 1)) * 16 + 8 * (kg & 1);   // taps 0/1
  size_t off1 = (size_t)(rowA + 2) * 16 + 8 * (kg & 1);           // tap 2 (+pad)
  uint2 na0 = *reinterpret_cast<const uint2*>(base + off0);
  uint2 na1 = *reinterpret_cast<const uint2*>(base + off1);
  float mem[2][4] = {{0.f, 0.f, 0.f, 0.f}, {0.f, 0.f, 0.f, 0.f}};
  int pos_base = pt * 64 + wv * 16 + kg * 4;
  bool dostore = pos_base < L2PAD;
  for (int t = 0; t < T_STEPS; ++t) {
    uint2 a0 = na0, a1 = na1;
    const uint8_t* nb = base + (size_t)((t + 1 < T_STEPS) ? t + 1 : t) * 8192;
    na0 = *reinterpret_cast<const uint2*>(nb + off0);
    na1 = *reinterpret_cast<const uint2*>(nb + off1);
    bf16x8 af0 = frag_from_bytes(a0);
    bf16x8 af1 = frag_from_bytes(a1);
    uint32_t st[2];
#pragma unroll
    for (int nt = 0; nt < 2; ++nt) {
      f32x4 acc = (f32x4){0.f, 0.f, 0.f, 0.f};
      acc = __builtin_amdgcn_mfma_f32_16x16x32_bf16(af0, bw[nt][0][0], acc, 0, 0, 0);
      acc = __builtin_amdgcn_mfma_f32_16x16x32_bf16(af1, bw[nt][1][0], acc, 0, 0, 0);
      acc = __builtin_amdgcn_mfma_f32_16x16x32_bf16(af0, bw[nt][0][1], acc, 0, 0, 0);
      acc = __builtin_amdgcn_mfma_f32_16x16x32_bf16(af1, bw[nt][1][1], acc, 0, 0, 0);
      uint32_t packed = 0;
#pragma unroll
      for (int r = 0; r < 4; ++r) {
        float rst = (mem[nt][r] > THR) ? 1.f : 0.f;
        mem[nt][r] = BETA * mem[nt][r] + (acc[r] + sh[nt]) - rst;
        packed |= (mem[nt][r] > THR ? 1u : 0u) << (8 * r);
      }
      st[nt] = packed;
    }
    if (dostore) {
      uint32_t idx0 = (uint32_t)(t * 64 + item) * (KTOT / 4) + r16 * (L2PAD / 4) + (pos_base >> 2);
      spk2[idx0] = st[0];
      spk2[idx0 + 16 * (L2PAD / 4)] = st[1];
    }
  }
}

// ---------------- K5: fc1 MFMA GEMM, LDS-free: all fragments direct from global ----------------
// grid (KSPLIT, 50), 256 thr = 4 waves; wave wv owns N-cols [wv*64, wv*64+64)
__global__ __launch_bounds__(256) void k_fc1(const uint8_t* __restrict__ spk2,
                                             const uint8_t* __restrict__ wTf,
                                             float* __restrict__ part) {
  int ks = blockIdx.x;
  int m0 = blockIdx.y * 64;
  int tid = threadIdx.x;
  int lane = tid & 63, wv = tid >> 6;
  int r16 = lane & 15, kg = lane >> 4;

  f32x4 acc[4][4];
#pragma unroll
  for (int mi = 0; mi < 4; ++mi)
#pragma unroll
    for (int ni = 0; ni < 4; ++ni) acc[mi][ni] = (f32x4){0.f, 0.f, 0.f, 0.f};

  const uint8_t* abase = spk2 + (size_t)(m0 + r16) * KTOT + ks * KRANGE + kg * 8;
  const uint8_t* bbase = wTf + (size_t)ks * KSTEPS * 32768 + wv * 8192 + lane * 16;

  for (int ch = 0; ch < KSTEPS; ++ch) {
    uint2 a[4];
#pragma unroll
    for (int mi = 0; mi < 4; ++mi)
      a[mi] = *reinterpret_cast<const uint2*>(abase + (size_t)mi * 16 * KTOT + ch * 32);
    bf16x8 bfr[4][2];
#pragma unroll
    for (int ni = 0; ni < 4; ++ni)
#pragma unroll
      for (int sel = 0; sel < 2; ++sel)
        bfr[ni][sel] = *reinterpret_cast<const bf16x8*>(bbase + (size_t)ch * 32768 + ni * 2048 + sel * 1024);
    bf16x8 af[4];
#pragma unroll
    for (int mi = 0; mi < 4; ++mi) af[mi] = frag_from_bytes(a[mi]);
#pragma unroll
    for (int ni = 0; ni < 4; ++ni)
#pragma unroll
      for (int mi = 0; mi < 4; ++mi) {
        acc[mi][ni] = __builtin_amdgcn_mfma_f32_16x16x32_bf16(af[mi], bfr[ni][0], acc[mi][ni], 0, 0, 0);
        acc[mi][ni] = __builtin_amdgcn_mfma_f32_16x16x32_bf16(af[mi], bfr[ni][1], acc[mi][ni], 0, 0, 0);
      }
  }
  int colb = wv * 64 + r16;
  int rowb = m0 + kg * 4;
#pragma unroll
  for (int mi = 0; mi < 4; ++mi)
#pragma unroll
    for (int ni = 0; ni < 4; ++ni) {
      float* pp = part + (size_t)(ks * MROWS + rowb + mi * 16) * NPAD + colb + ni * 16;
#pragma unroll
      for (int r = 0; r < 4; ++r) pp[r * NPAD] = acc[mi][ni][r];
    }
}

// ---------------- K6: reduce K-splits + fc1 bias + LIF3 + rate/latency -> comb [64][500] ----------------
__global__ __launch_bounds__(256) void k_lif3(const float* __restrict__ part,
                                              const float* __restrict__ fc1b,
                                              float* __restrict__ comb) {
  int item = blockIdx.x;
  int n = threadIdx.x;
  if (n >= NFC) return;
  float mem = 0.f, cnt = 0.f;
  int first = -1;
  float bias = fc1b[n];
  for (int t = 0; t < T_STEPS; ++t) {
    int row = t * NITEM + item;
    float s = bias;
#pragma unroll
    for (int ksx = 0; ksx < KSPLIT; ++ksx) s += part[(ksx * MROWS + row) * NPAD + n];
    float r = (mem > THR) ? 1.f : 0.f;
    mem = BETA * mem + s - r;
    if (mem > THR) { cnt += 1.f; if (first < 0) first = t; }
  }
  comb[item * 500 + n] = cnt;
  comb[item * 500 + NFC + n] = (first < 0) ? 0.f : ((float)first / (float)T_STEPS);
}

// ---------------- K7: head GEMM [64]x[500]->[128] + L2 normalize -> d_out ----------------
__global__ __launch_bounds__(128) void k_head(const float* __restrict__ comb,
                                              const float* __restrict__ fcsw,
                                              const float* __restrict__ fcsb,
                                              float* __restrict__ dout) {
  __shared__ float cr[500];
  __shared__ float red[2];
  int item = blockIdx.x;
  int o = threadIdx.x;
  for (int i = o; i < 500; i += 128) cr[i] = comb[item * 500 + i];
  __syncthreads();
  float acc = fcsb[o];
  for (int j = 0; j < 500; ++j) acc += cr[j] * fcsw[o * 500 + j];
  float sq = acc * acc;
  for (int off = 32; off > 0; off >>= 1) sq += __shfl_down(sq, off, 64);
  if ((o & 63) == 0) red[o >> 6] = sq;
  __syncthreads();
  float norm = sqrtf(red[0] + red[1]);
  norm = fmaxf(norm, 1e-12f);
  dout[item * 128 + o] = acc / norm;
}

// ---------------- launch ----------------
extern "C" void kernel_launch(void* const* d_in, const int* in_sizes, int n_in,
                              void* d_out, int out_size, void* d_ws, size_t ws_size,
                              hipStream_t stream) {
  const float* x1   = (const float*)d_in[0];
  const float* x2   = (const float*)d_in[1];
  const float* c1w  = (const float*)d_in[2];
  const float* c1b  = (const float*)d_in[3];
  const float* bn1g = (const float*)d_in[4];
  const float* bn1b = (const float*)d_in[5];
  const float* bn1m = (const float*)d_in[6];
  const float* bn1v = (const float*)d_in[7];
  const float* c2w  = (const float*)d_in[8];
  const float* c2b  = (const float*)d_in[9];
  const float* bn2g = (const float*)d_in[10];
  const float* bn2b = (const float*)d_in[11];
  const float* bn2m = (const float*)d_in[12];
  const float* bn2v = (const float*)d_in[13];
  const float* fc1w = (const float*)d_in[14];
  const float* fc1b = (const float*)d_in[15];
  const float* fcsw = (const float*)d_in[16];
  const float* fcsb = (const float*)d_in[17];

  char* ws = (char*)d_ws;
  float*    cur1    = (float*)(ws + OFF_CUR1);
  uint8_t*  wfrag   = (uint8_t*)(ws + OFF_CUR1);   // reused AFTER k_lif1
  uint8_t*  pooledT = (uint8_t*)(ws + OFF_POOL);
  uint8_t*  spk2    = (uint8_t*)(ws + OFF_SPK2);
  uint8_t*  wTf     = (uint8_t*)(ws + OFF_WT);
  float*    part    = (float*)(ws + OFF_PART);
  float*    comb    = (float*)(ws + OFF_COMB);

  k_wt<<<dim3(NKTILE), dim3(256), 0, stream>>>(fc1w, wTf);
  k_conv1<<<dim3(8, NITEM), dim3(256), 0, stream>>>(x1, x2, c1w, c1b, bn1g, bn1b, bn1m, bn1v, cur1);
  k_lif1<<<dim3(8, NITEM), dim3(256), 0, stream>>>(cur1, pooledT);
  k_wc2<<<dim3(1), dim3(512), 0, stream>>>(c2w, c2b, bn2g, bn2b, bn2m, bn2v, wfrag);
  k_conv2<<<dim3(8, NITEM), dim3(256), 0, stream>>>(pooledT, wfrag, (uint32_t*)spk2);
  k_fc1<<<dim3(KSPLIT, MROWS / 64), dim3(256), 0, stream>>>(spk2, wTf, part);
  k_lif3<<<dim3(NITEM), dim3(256), 0, stream>>>(part, fc1b, comb);
  k_head<<<dim3(NITEM), dim3(128), 0, stream>>>(comb, fcsw, fcsb, (float*)d_out);
}